// Round 17
// baseline (102.244 us; speedup 1.0000x reference)
//
#include <hip/hip_runtime.h>
#include <math.h>

// Problem constants (from reference)
constexpr int B_  = 16;
constexpr int LQ_ = 1024;
constexpr int LK_ = 4096;
constexpr int D_  = 256;
constexpr float HALF_BW_F = 64.0f;         // 128 // 2
constexpr float SCALE = 0.0625f;           // (D^-0.25)^2 = 1/sqrt(256)

// native clang vector for nontemporal builtins (HIP_vector_type is rejected)
typedef float fx4 __attribute__((ext_vector_type(4)));

constexpr int NB_PAD = 168;                // softmax 9*16=144 slots, padded
constexpr int ROWS_PER_BLK = 16;                 // 4 waves x 4 rows
constexpr int NUNIT = (B_ * LQ_) / ROWS_PER_BLK; // 1024 row-units
constexpr int NXCD = 8;
constexpr int UNIT_PER_XCD = NUNIT / NXCD;       // 128
constexpr int CHUNK = 16;                  // keys per LDS chunk (16 KB)

template <int CTRL>
__device__ __forceinline__ float dpp_add(float v) {
    int x = __builtin_amdgcn_update_dpp(0, __float_as_int(v), CTRL, 0xF, 0xF, true);
    return v + __int_as_float(x);
}
__device__ __forceinline__ float dpp_reduce16(float v) {
    v = dpp_add<0x118>(v); v = dpp_add<0x114>(v);
    v = dpp_add<0x112>(v); v = dpp_add<0x111>(v);
    return v;   // complete 16-lane sum in l==15
}
__device__ __forceinline__ float grp16_max(float v) {
    #pragma unroll
    for (int off = 8; off > 0; off >>= 1)
        v = fmaxf(v, __shfl_xor(v, off, 64));
    return v;
}
__device__ __forceinline__ float grp16_sum(float v) {
    #pragma unroll
    for (int off = 8; off > 0; off >>= 1)
        v += __shfl_xor(v, off, 64);
    return v;
}

// async global->LDS, 16B per lane; global addr is per-lane, LDS dest is
// wave-uniform base + lane*16 (linear).
__device__ __forceinline__ void gload16(const float* g, float* l) {
    __builtin_amdgcn_global_load_lds(
        (const __attribute__((address_space(1))) float*)g,
        (__attribute__((address_space(3))) float*)l,
        16, 0, 0);
}

// Diagnosis R12-R16: compute ~100us is occupancy-invariant + store-invariant
// -> saturated shared resource = L2/L3 path for K reads (573 MB logical:
// every wave privately re-reads its ~141KB band; per-XCD active span ~2-5MB
// thrashes the 4MB L2, reads fall to the Infinity-Cache fabric).
// Fix: block-cooperative K staging. The block's union band (<=189 keys) is
// staged in 16-key chunks into LDS (global_load_lds, double-buffered,
// prefetch chunk c+1 while computing chunk c) -> K read volume /2.9 and
// the load latency hides under compute structurally (m97 pattern).
__global__ __launch_bounds__(256, 2) void stripe_attn_kernel(
    const float* __restrict__ Q, const float* __restrict__ K,
    const float* __restrict__ V,
    const int* __restrict__ qlen, const int* __restrict__ klen,
    float* __restrict__ Wout, float* __restrict__ Vout)
{
    const int Bid  = blockIdx.x;
    const int xcd  = Bid & 7;
    const int type = (Bid >> 3) & 1;
    const int rb   = xcd * UNIT_PER_XCD + (Bid >> 4);
    const int tid  = threadIdx.x;
    const int lane = tid & 63;
    const int wave = tid >> 6;
    const int row0 = rb * ROWS_PER_BLK + wave * 4;   // this wave's 4 rows
    const int b    = row0 >> 10;           // same batch for all 16 unit rows
    const int qi0  = row0 & (LQ_ - 1);

    const int   key_len = klen[b];
    const float slope   = (float)key_len / (float)qlen[b];   // fp32 div (ref)

    // per-row integer band (exact fp32 arithmetic as reference)
    int k_lo[4], k_hi[4];
    #pragma unroll
    for (int r = 0; r < 4; ++r) {
        const float center = (float)(qi0 + r) * slope;
        int lo = (int)ceilf(center - HALF_BW_F); if (lo < 0) lo = 0;
        int hi = (int)floorf(center + HALF_BW_F); if (hi > key_len - 1) hi = key_len - 1;
        k_lo[r] = lo; k_hi[r] = hi;
    }

    if (type == 1) {
        // ================= FILL BLOCK: pure store pump =================
        const float* vs = V    + (size_t)row0 * 1024;
        float*       vd = Vout + (size_t)row0 * 1024;
        #pragma unroll
        for (int it = 0; it < 16; ++it) {
            const int o = (it * 64 + lane) * 4;
            fx4 t = __builtin_nontemporal_load((const fx4*)(vs + o));
            __builtin_nontemporal_store(t, (fx4*)(vd + o));
        }
        const fx4 z4 = {0.f, 0.f, 0.f, 0.f};
        #pragma unroll
        for (int r = 0; r < 4; ++r) {
            const int s_lo = k_lo[r] >> 8, s_hi = k_hi[r] >> 8;
            float* base = Wout + (size_t)(row0 + r) * LK_;
            #pragma unroll
            for (int j = 0; j < 16; ++j) {
                if (j < s_lo || j > s_hi)
                    __builtin_nontemporal_store(z4, (fx4*)(base + (j * 64 + lane) * 4));
            }
        }
        return;
    }

    // ================= COMPUTE BLOCK =================
    __shared__ float kbuf[2][CHUNK * 256]; // 2 x 16 KB double buffer
    __shared__ float s_sc[4][4 * NB_PAD];  // [wave][row*NB_PAD + slot]

    const int g   = lane >> 4;             // group 0..3
    const int l   = lane & 15;             // fine chunk: dims m*64 + l*4
    const int lo0 = k_lo[0], hi3 = k_hi[3];    // wave union band

    // block union band (rows rb*16 .. rb*16+15), block-uniform
    const int qi_blk = (rb * ROWS_PER_BLK) & (LQ_ - 1);
    int lo_b = (int)ceilf((float)qi_blk * slope - HALF_BW_F);
    if (lo_b < 0) lo_b = 0;
    int hi_b = (int)floorf((float)(qi_blk + 15) * slope + HALF_BW_F);
    if (hi_b > key_len - 1) hi_b = key_len - 1;
    const int nchunks = (hi_b - lo_b + CHUNK) / CHUNK;   // <= 12

    // ---- Q staging: lane (g,l) holds dims [m*64 + l*4) of each row ----
    const float* qbase = Q + ((size_t)b * LQ_ + qi0) * D_ + l * 4;
    float4 q0[4], q1[4], q2[4], q3[4];
    #pragma unroll
    for (int m = 0; m < 4; ++m) {
        q0[m] = *(const float4*)(qbase + 0 * D_ + m * 64);
        q1[m] = *(const float4*)(qbase + 1 * D_ + m * 64);
        q2[m] = *(const float4*)(qbase + 2 * D_ + m * 64);
        q3[m] = *(const float4*)(qbase + 3 * D_ + m * 64);
    }

    const float* kbase = K + (size_t)b * LK_ * D_;
    float* sw = s_sc[wave];

    // stage chunk c into buffer buf: wave stages keys wave*4..wave*4+3
    auto stage = [&](int c, int buf) {
        const int base_key = lo_b + c * CHUNK + wave * 4;
        #pragma unroll
        for (int s = 0; s < 4; ++s) {
            int key = base_key + s;
            if (key > hi_b) key = hi_b;            // clamp: safe, in-batch
            gload16(kbase + (size_t)key * D_ + lane * 4,
                    &kbuf[buf][(wave * 4 + s) * 256]);
        }
    };

    stage(0, 0);
    __syncthreads();

    for (int c = 0; c < nchunks; ++c) {
        const int cb = c & 1;
        if (c + 1 < nchunks) stage(c + 1, cb ^ 1);

        const int cbase = lo_b + c * CHUNK;
        if (cbase + CHUNK - 1 >= lo0 && cbase <= hi3) {   // wave-uniform skip
            const float* kl = kbuf[cb];
            #pragma unroll
            for (int t = 0; t < 2; ++t) {
                const int jA = g + 8 * t, jB = g + 4 + 8 * t;
                const int keyA = cbase + jA, keyB = cbase + jB;
                float4 kfA[4], kfB[4];
                #pragma unroll
                for (int m = 0; m < 4; ++m) {
                    kfA[m] = *(const float4*)(kl + jA * 256 + m * 64 + l * 4);
                    kfB[m] = *(const float4*)(kl + jB * 256 + m * 64 + l * 4);
                }
                float a0 = 0.f, a1 = 0.f, a2 = 0.f, a3 = 0.f;
                float b0 = 0.f, b1 = 0.f, b2 = 0.f, b3 = 0.f;
                #pragma unroll
                for (int m = 0; m < 4; ++m) {
                    a0 += q0[m].x*kfA[m].x + q0[m].y*kfA[m].y + q0[m].z*kfA[m].z + q0[m].w*kfA[m].w;
                    a1 += q1[m].x*kfA[m].x + q1[m].y*kfA[m].y + q1[m].z*kfA[m].z + q1[m].w*kfA[m].w;
                    a2 += q2[m].x*kfA[m].x + q2[m].y*kfA[m].y + q2[m].z*kfA[m].z + q2[m].w*kfA[m].w;
                    a3 += q3[m].x*kfA[m].x + q3[m].y*kfA[m].y + q3[m].z*kfA[m].z + q3[m].w*kfA[m].w;
                    b0 += q0[m].x*kfB[m].x + q0[m].y*kfB[m].y + q0[m].z*kfB[m].z + q0[m].w*kfB[m].w;
                    b1 += q1[m].x*kfB[m].x + q1[m].y*kfB[m].y + q1[m].z*kfB[m].z + q1[m].w*kfB[m].w;
                    b2 += q2[m].x*kfB[m].x + q2[m].y*kfB[m].y + q2[m].z*kfB[m].z + q2[m].w*kfB[m].w;
                    b3 += q3[m].x*kfB[m].x + q3[m].y*kfB[m].y + q3[m].z*kfB[m].z + q3[m].w*kfB[m].w;
                }
                a0 = dpp_reduce16(a0); a1 = dpp_reduce16(a1);
                a2 = dpp_reduce16(a2); a3 = dpp_reduce16(a3);
                b0 = dpp_reduce16(b0); b1 = dpp_reduce16(b1);
                b2 = dpp_reduce16(b2); b3 = dpp_reduce16(b3);
                if (l == 15) {
                    if (keyA >= k_lo[0] && keyA <= k_hi[0]) sw[0*NB_PAD + keyA - k_lo[0]] = a0 * SCALE;
                    if (keyA >= k_lo[1] && keyA <= k_hi[1]) sw[1*NB_PAD + keyA - k_lo[1]] = a1 * SCALE;
                    if (keyA >= k_lo[2] && keyA <= k_hi[2]) sw[2*NB_PAD + keyA - k_lo[2]] = a2 * SCALE;
                    if (keyA >= k_lo[3] && keyA <= k_hi[3]) sw[3*NB_PAD + keyA - k_lo[3]] = a3 * SCALE;
                    if (keyB >= k_lo[0] && keyB <= k_hi[0]) sw[0*NB_PAD + keyB - k_lo[0]] = b0 * SCALE;
                    if (keyB >= k_lo[1] && keyB <= k_hi[1]) sw[1*NB_PAD + keyB - k_lo[1]] = b1 * SCALE;
                    if (keyB >= k_lo[2] && keyB <= k_hi[2]) sw[2*NB_PAD + keyB - k_lo[2]] = b2 * SCALE;
                    if (keyB >= k_lo[3] && keyB <= k_hi[3]) sw[3*NB_PAD + keyB - k_lo[3]] = b3 * SCALE;
                }
            }
        }
        __syncthreads();   // compute(c) done everywhere; stage(c+1) drained
    }

    // ---- softmax: 16-lane group g owns row g (9 values per lane) ----
    const float center_g = (float)(qi0 + g) * slope;
    int klo_g = (int)ceilf(center_g - HALF_BW_F); if (klo_g < 0) klo_g = 0;
    int khi_g = (int)floorf(center_g + HALF_BW_F); if (khi_g > key_len - 1) khi_g = key_len - 1;
    const int nb_g = khi_g - klo_g + 1;    // 65..129
    float* sg = sw + g * NB_PAD;

    float vj[9];
    #pragma unroll
    for (int j = 0; j < 9; ++j) {
        const int idx = l + j * 16;
        vj[j] = (idx < nb_g) ? sg[idx] : -INFINITY;
    }
    float mx = vj[0];
    #pragma unroll
    for (int j = 1; j < 9; ++j) mx = fmaxf(mx, vj[j]);
    mx = grp16_max(mx);

    float ej[9], ssum = 0.f;
    #pragma unroll
    for (int j = 0; j < 9; ++j) { ej[j] = __expf(vj[j] - mx); ssum += ej[j]; }
    ssum = grp16_sum(ssum);
    const float inv = 1.0f / ssum;
    #pragma unroll
    for (int j = 0; j < 9; ++j)
        sg[l + j * 16] = ej[j] * inv;      // padding slots get 0, never read

    // ---- band stripes only (<=2 per row; fill partner wrote the rest) ----
    #pragma unroll
    for (int r = 0; r < 4; ++r) {
        const int klo = k_lo[r], khi = k_hi[r];
        const int s_lo = klo >> 8, s_hi = khi >> 8;
        float* base = Wout + (size_t)(row0 + r) * LK_;
        const float* sr = sw + r * NB_PAD;
        for (int j = s_lo; j <= s_hi; ++j) {           // <=2 iterations
            const int c0 = (j * 64 + lane) * 4;
            float w[4] = {0.f, 0.f, 0.f, 0.f};
            if (c0 + 3 >= klo && c0 <= khi) {
                #pragma unroll
                for (int i = 0; i < 4; ++i) {
                    const int c = c0 + i;
                    if (c >= klo && c <= khi) w[i] = sr[c - klo];
                }
            }
            fx4 w4; w4.x = w[0]; w4.y = w[1]; w4.z = w[2]; w4.w = w[3];
            __builtin_nontemporal_store(w4, (fx4*)(base + c0));
        }
    }
}

extern "C" void kernel_launch(void* const* d_in, const int* in_sizes, int n_in,
                              void* d_out, int out_size, void* d_ws, size_t ws_size,
                              hipStream_t stream) {
    // inputs (setup_inputs order): query, key, value, mask, query_lengths, key_lengths
    const float* Q    = (const float*)d_in[0];
    const float* K    = (const float*)d_in[1];
    const float* V    = (const float*)d_in[2];
    const int*   qlen = (const int*)d_in[4];
    const int*   klen = (const int*)d_in[5];

    float* Wout = (float*)d_out;
    const size_t W_ELEMS = (size_t)B_ * LQ_ * LK_;        // 67,108,864
    float* Vout = Wout + W_ELEMS;

    stripe_attn_kernel<<<dim3(2 * NUNIT), dim3(256), 0, stream>>>(
        Q, K, V, qlen, klen, Wout, Vout);
}